// Round 10
// baseline (415.208 us; speedup 1.0000x reference)
//
#include <hip/hip_runtime.h>
#include <cstdint>
#include <cstddef>

typedef __attribute__((ext_vector_type(4))) float f32x4;
typedef __attribute__((ext_vector_type(8))) short short8;

// ---------- bf16 helpers (bit-level, header-version independent) ----------
__device__ __forceinline__ unsigned short f2bf(float f) {
  unsigned int u = __float_as_uint(f);
  u += 0x7fffu + ((u >> 16) & 1u);            // round to nearest even
  return (unsigned short)(u >> 16);
}
__device__ __forceinline__ float bf2f(unsigned short h) {
  return __uint_as_float(((unsigned int)h) << 16);
}
__device__ __forceinline__ float bflo(unsigned int w) {   // low bf16 of a word
  return __uint_as_float(w << 16);
}
__device__ __forceinline__ float bfhi(unsigned int w) {   // high bf16 of a word
  return __uint_as_float(w & 0xffff0000u);
}

__device__ __forceinline__ void gload16(const unsigned short* g, unsigned short* l) {
  __builtin_amdgcn_global_load_lds(
      (const __attribute__((address_space(1))) void*)g,
      (__attribute__((address_space(3))) void*)l, 16, 0, 0);
}

// ---------- P1: x f32 -> bf16 ----------
__global__ __launch_bounds__(256) void k_cast(const float* __restrict__ src,
                                              unsigned short* __restrict__ hi) {
  size_t i = ((size_t)blockIdx.x * 256 + threadIdx.x) * 4;
  float4 v = *(const float4*)(src + i);
  *(ushort4*)(hi + i) = make_ushort4(f2bf(v.x), f2bf(v.y), f2bf(v.z), f2bf(v.w));
}

// ---------- P2/P3: transpose f32 [R][C] -> bf16 [C][R] ----------
__global__ __launch_bounds__(256) void k_transpose(const float* __restrict__ src,
                                                   unsigned short* __restrict__ hi,
                                                   int R, int C) {
  __shared__ float tile[32][33];
  int tx = threadIdx.x & 31, ty = threadIdx.x >> 5;  // ty 0..7
  int c0 = blockIdx.x * 32, r0 = blockIdx.y * 32;
#pragma unroll
  for (int i = 0; i < 4; ++i)
    tile[ty + 8 * i][tx] = src[(size_t)(r0 + ty + 8 * i) * C + (c0 + tx)];
  __syncthreads();
#pragma unroll
  for (int i = 0; i < 4; ++i) {
    float v = tile[tx][ty + 8 * i];
    hi[(size_t)(c0 + ty + 8 * i) * R + (r0 + tx)] = f2bf(v);
  }
}

// ---------- GEMM: A[M][K] (bf16, k-contig), B[N][K] (bf16, k-contig) -> C[M][N]
// 128x256 tile, BK=32, 8 waves (2M x 4N, wave-tile 64x64), ring-3 LDS
// (3 x 24KB = 72KB) -> TWO blocks/CU (the R8/R9 1-block config was CU-phase-
// locked: all waves barrier-synced into read-then-MFMA phases, serial-sum
// matched measured 2586cyc/KT. A second resident block drifts out of phase and
// fills the MFMA pipe while the first drains LDS — cross-block slip).
// Per K-tile: wait vmcnt(3) (tile-u's own 3 gloads; tile u+1 in flight) + raw
// s_barrier, then stage tile u+2 (3 gloads/wave), 8 ds_read_b128, 16 MFMA.
// Race-freedom (same proof as R8): write target (u+2)%3 == (u-1)%3; all waves'
// tile-u-1 reads COMPLETED before their iter-u barrier arrival (lgkm dep
// before MFMA, MFMA before barrier), writes issued after passing that barrier.
// Read-side: each wave's vmcnt(3) certifies its own tile-u loads pre-barrier
// -> collective completeness after barrier.
// LDS swizzle (verified, conflicts=0): row of 32 k = 4 slots of 8 shorts; phys
// slot p at row r holds global k-chunk p ^ ((r>>1)&3); staged with LINEAR LDS
// dest + pre-swizzled global k; fragment reads apply the same XOR; A and B use
// the identical lane->k-chunk convention (contraction safe).
template<bool BF16OUT>
__global__ __launch_bounds__(512, 4) void k_gemm(const unsigned short* __restrict__ A,
                                                 const unsigned short* __restrict__ B,
                                                 void* __restrict__ Cv, int M, int N, int K) {
  __shared__ unsigned short lds[3][12288];   // 3 bufs x (A 4096 + B 8192 shorts)
  const int tid = threadIdx.x, wave = tid >> 6, lane = tid & 63;
  const size_t row0 = (size_t)blockIdx.x * 128;
  const size_t col0 = (size_t)blockIdx.y * 256;
  const int wr = wave >> 2, wc = wave & 3;   // 2M x 4N waves
  const int r16 = lane & 15;
  const int ksw = (lane >> 4) ^ ((r16 >> 1) & 3);   // swizzled k-slot (0..3)
  const int aoff = (wr * 64 + r16) * 32 + ksw * 8;  // A region: shorts 0..4095
  const int boff = 4096 + (wc * 64 + r16) * 32 + ksw * 8;
  const int gchunk = (lane & 3) ^ ((lane >> 3) & 3);  // pre-swizzled global k-chunk
  const int srow = lane >> 2;                          // 0..15

  f32x4 acc[4][4];
#pragma unroll
  for (int i = 0; i < 4; ++i)
#pragma unroll
    for (int j = 0; j < 4; ++j) acc[i][j] = (f32x4){0.f, 0.f, 0.f, 0.f};

  // stage K-tile kt into ring buffer buf: 24 x 1KB instrs, 3 per wave.
  // instr i: i<8 -> A row-block i (16 rows); i>=8 -> B row-block i-8.
  // lane l: row = 16*ib + (l>>2), 16B at phys slot l&3 (global k pre-swizzled).
  auto STAGE3 = [&](int buf, int kt) {
#pragma unroll
    for (int j = 0; j < 3; ++j) {
      int i = wave * 3 + j;
      const unsigned short* src = (i < 8) ? A : B;
      int ib = (i < 8) ? i : (i - 8);
      size_t grow = ((i < 8) ? row0 : col0) + (size_t)(ib * 16 + srow);
      gload16(src + grow * (size_t)K + (size_t)(kt * 32 + gchunk * 8),
              &lds[buf][i * 512]);
    }
  };

  STAGE3(0, 0);
  STAGE3(1, 1);
  const int nT = K >> 5;
  int bi = 0, wi = 2;
  for (int u = 0; u < nT; ++u) {
    if (u < nT - 1) asm volatile("s_waitcnt vmcnt(3)" ::: "memory");
    else            asm volatile("s_waitcnt vmcnt(0)" ::: "memory");
    asm volatile("s_barrier" ::: "memory");
    if (u + 2 < nT) STAGE3(wi, u + 2);
    const unsigned short* buf = lds[bi];
    short8 a4[4], b4[4];
#pragma unroll
    for (int nb = 0; nb < 4; ++nb)
      b4[nb] = *(const short8*)&buf[boff + nb * 512];
#pragma unroll
    for (int mb = 0; mb < 4; ++mb)
      a4[mb] = *(const short8*)&buf[aoff + mb * 512];
    __builtin_amdgcn_s_setprio(1);
#pragma unroll
    for (int mb = 0; mb < 4; ++mb)
#pragma unroll
      for (int nb = 0; nb < 4; ++nb)
        acc[mb][nb] = __builtin_amdgcn_mfma_f32_16x16x32_bf16(a4[mb], b4[nb], acc[mb][nb], 0, 0, 0);
    __builtin_amdgcn_s_setprio(0);
    bi = (bi == 2) ? 0 : bi + 1;
    wi = (wi == 2) ? 0 : wi + 1;
  }

  // C/D layout (HW-verified): col = lane&15, row = (lane>>4)*4 + reg
#pragma unroll
  for (int m = 0; m < 4; ++m)
#pragma unroll
    for (int n = 0; n < 4; ++n) {
      size_t row = row0 + wr * 64 + m * 16 + (lane >> 4) * 4;
      size_t col = col0 + wc * 64 + n * 16 + r16;
      if (BF16OUT) {
        unsigned short* C = (unsigned short*)Cv;
#pragma unroll
        for (int r = 0; r < 4; ++r) C[(row + r) * (size_t)N + col] = f2bf(acc[m][n][r]);
      } else {
        float* C = (float*)Cv;
#pragma unroll
        for (int r = 0; r < 4; ++r) C[(row + r) * (size_t)N + col] = acc[m][n][r];
      }
    }
}

// ---------- scan constants ----------
#define SB 4
#define ST 4096
#define SE 2048
#define CHUNK 64
#define NCHUNK 64
#define NCHAIN (SB * SE)  // 8192

// transforms via native v_exp_f32/v_log_f32 (__expf/__logf), ~1e-7 abs error in
// log-space (irrelevant vs 0.134 budget). proj is bf16.
__device__ __forceinline__ void transform(float k, float hx, float& lc, float& lv) {
  float u = __expf(-fabsf(k));
  float sp = fmaxf(k, 0.f) + __logf(1.f + u);   // softplus(k)
  lc = -sp;                                     // log(1 - sigmoid(k))
  float eh = __expf(fminf(hx, 0.f));            // exp(hx) for hx<0 (clamped: no overflow)
  float arg = (hx >= 0.f) ? (hx + 0.5f) : (1.f + eh);
  float vl = __logf(arg);
  float lg = (hx >= 0.f) ? vl : (hx - vl);      // log g(hx)
  lv = lg + k + lc;                             // log g + log sigmoid(k)
}
__device__ __forceinline__ float lse_step(float lc, float lv, float S) {
  float a1 = lc + S;
  float m = fmaxf(a1, lv);
  float d = fminf(a1, lv) - m;                  // <= 0 (or -inf)
  return m + __logf(1.f + __expf(d));
}

// K2: transforms + chunk-local scan -> chunk summaries. TWO adjacent e-chains
// per thread: proj reads become 4B/lane words (was 2B/lane scalar bf16).
__global__ __launch_bounds__(256) void k_scan1(const unsigned int* __restrict__ proj32,
                                               const float* __restrict__ bfv,
                                               float* __restrict__ Ac,
                                               float* __restrict__ Bc) {
  int idx = blockIdx.x * 256 + threadIdx.x;   // 262144 = (c, b, p) p fastest
  int p = idx & 1023, b = (idx >> 10) & 3, c = idx >> 12;
  float2 bk = ((const float2*)bfv)[p];
  float2 bh = ((const float2*)(bfv + SE))[p];
  float A0 = 0.f, A1 = 0.f, S0 = -INFINITY, S1 = -INFINITY;
  size_t base = ((size_t)(b * ST + c * CHUNK)) * (SE) + p;  // word index (row = 2048 words)
  for (int i = 0; i < CHUNK; ++i) {
    unsigned int kw = proj32[base], hw = proj32[base + 1024];
    float lc0, lv0, lc1, lv1;
    transform(bflo(kw) + bk.x, bflo(hw) + bh.x, lc0, lv0);
    transform(bfhi(kw) + bk.y, bfhi(hw) + bh.y, lc1, lv1);
    A0 += lc0; S0 = lse_step(lc0, lv0, S0);
    A1 += lc1; S1 = lse_step(lc1, lv1, S1);
    base += SE;
  }
  int chain = b * SE + 2 * p;
  Ac[(size_t)c * NCHAIN + chain] = A0; Ac[(size_t)c * NCHAIN + chain + 1] = A1;
  Bc[(size_t)c * NCHAIN + chain] = S0; Bc[(size_t)c * NCHAIN + chain + 1] = S1;
}

// K3: scan over chunk summaries -> incoming state per chunk
__global__ __launch_bounds__(256) void k_scan2(const float* __restrict__ lh0,
                                               const float* __restrict__ Ac,
                                               const float* __restrict__ Bc,
                                               float* __restrict__ Hin) {
  int chain = blockIdx.x * 256 + threadIdx.x;  // 8192 = b*E + e
  float H = lh0[chain];
  for (int c = 0; c < NCHUNK; ++c) {
    Hin[(size_t)c * NCHAIN + chain] = H;
    float a = Ac[(size_t)c * NCHAIN + chain] + H;
    float bv = Bc[(size_t)c * NCHAIN + chain];
    float m = fmaxf(a, bv);
    float d = fminf(a, bv) - m;
    H = m + __logf(1.f + __expf(d));
  }
}

// K4: replay scan (recompute from bf16 proj) with true incoming state; emit
// h_t (bf16, paired word writes) and out2 slices (float2 writes). 2 chains/thread.
__global__ __launch_bounds__(256) void k_scan3(const unsigned int* __restrict__ proj32,
                                               const float* __restrict__ bfv,
                                               const float* __restrict__ Hin,
                                               unsigned int* __restrict__ ht32,
                                               float* __restrict__ out2) {
  int idx = blockIdx.x * 256 + threadIdx.x;
  int p = idx & 1023, b = (idx >> 10) & 3, c = idx >> 12;
  float2 bk = ((const float2*)bfv)[p];
  float2 bh = ((const float2*)(bfv + SE))[p];
  int chain = b * SE + 2 * p;
  float S0 = Hin[(size_t)c * NCHAIN + chain];
  float S1 = Hin[(size_t)c * NCHAIN + chain + 1];
  size_t base = ((size_t)(b * ST + c * CHUNK)) * (SE) + p;
  int t = c * CHUNK;
  size_t hto = ((size_t)(b * ST + t)) * 1024 + p;   // word index into ht
  for (int i = 0; i < CHUNK; ++i, ++t) {
    unsigned int kw = proj32[base], hw = proj32[base + 1024];
    float lc0, lv0, lc1, lv1;
    transform(bflo(kw) + bk.x, bflo(hw) + bh.x, lc0, lv0);
    transform(bfhi(kw) + bk.y, bfhi(hw) + bh.y, lc1, lv1);
    S0 = lse_step(lc0, lv0, S0);
    S1 = lse_step(lc1, lv1, S1);
    ht32[hto] = ((unsigned int)f2bf(__expf(S1)) << 16) | f2bf(__expf(S0));
    if (t >= 2 && ((t - 2) % 3) == 0) {   // t in {2,5,...,4094}
      int j = (t - 2) / 3;
      float2 o; o.x = S0; o.y = S1;
      ((float2*)out2)[((size_t)b * 1365 + j) * 1024 + p] = o;
    }
    base += SE;
    hto += 1024;
  }
}

// ---------- launch ----------
extern "C" void kernel_launch(void* const* d_in, const int* in_sizes, int n_in,
                              void* d_out, int out_size, void* d_ws, size_t ws_size,
                              hipStream_t stream) {
  const float* x   = (const float*)d_in[0];
  const float* lh0 = (const float*)d_in[1];
  const float* wf  = (const float*)d_in[2];
  const float* bfv = (const float*)d_in[3];
  const float* wd  = (const float*)d_in[4];
  float* out1 = (float*)d_out;
  float* out2 = out1 + (size_t)SB * ST * 1024;

  char* p = (char*)d_ws;
  unsigned short* proj = (unsigned short*)p; p += 16384ull * 4096 * 2;  // 134 MB bf16
  unsigned short* xhi  = (unsigned short*)p; p += 16384ull * 1024 * 2;
  unsigned short* wfh  = (unsigned short*)p; p += 4096ull * 1024 * 2;
  unsigned short* wdt  = (unsigned short*)p; p += 1024ull * 2048 * 2;
  unsigned short* ht   = (unsigned short*)p; p += 16384ull * 2048 * 2;  // 67 MB
  float* Ac            = (float*)p;          p += 64ull * 8192 * 4;
  float* Bc            = (float*)p;          p += 64ull * 8192 * 4;
  float* Hin           = (float*)p;          p += 64ull * 8192 * 4;

  // pre-passes
  hipLaunchKernelGGL(k_cast, dim3(16384), dim3(256), 0, stream, x, xhi);
  hipLaunchKernelGGL(k_transpose, dim3(128, 32), dim3(256), 0, stream, wf, wfh, 1024, 4096);
  hipLaunchKernelGGL(k_transpose, dim3(32, 64),  dim3(256), 0, stream, wd, wdt, 2048, 1024);
  // GEMM1 (bf16 in/out): proj = x @ w_f   (128x256 tiles, 2 blocks/CU)
  hipLaunchKernelGGL((k_gemm<true>), dim3(128, 16), dim3(512), 0, stream,
                     xhi, wfh, (void*)proj, 16384, 4096, 1024);
  // 3-pass chunked log-space scan (proj bf16, read-only; word-paired loads)
  hipLaunchKernelGGL(k_scan1, dim3(1024), dim3(256), 0, stream,
                     (const unsigned int*)proj, bfv, Ac, Bc);
  hipLaunchKernelGGL(k_scan2, dim3(32), dim3(256), 0, stream, lh0, Ac, Bc, Hin);
  hipLaunchKernelGGL(k_scan3, dim3(1024), dim3(256), 0, stream,
                     (const unsigned int*)proj, bfv, Hin, (unsigned int*)ht, out2);
  // GEMM2 (bf16 in, f32 out): out1 = h_t @ w_down   (128x256 tiles, 2 blocks/CU)
  hipLaunchKernelGGL((k_gemm<false>), dim3(128, 4), dim3(512), 0, stream,
                     ht, wdt, (void*)out1, 16384, 1024, 2048);
}

// Round 11
// 389.209 us; speedup vs baseline: 1.0668x; 1.0668x over previous
//
#include <hip/hip_runtime.h>
#include <cstdint>
#include <cstddef>

typedef __attribute__((ext_vector_type(4))) float f32x4;
typedef __attribute__((ext_vector_type(8))) short short8;

// ---------- bf16 helpers (bit-level, header-version independent) ----------
__device__ __forceinline__ unsigned short f2bf(float f) {
  unsigned int u = __float_as_uint(f);
  u += 0x7fffu + ((u >> 16) & 1u);            // round to nearest even
  return (unsigned short)(u >> 16);
}
__device__ __forceinline__ float bf2f(unsigned short h) {
  return __uint_as_float(((unsigned int)h) << 16);
}

__device__ __forceinline__ void gload16(const unsigned short* g, unsigned short* l) {
  __builtin_amdgcn_global_load_lds(
      (const __attribute__((address_space(1))) void*)g,
      (__attribute__((address_space(3))) void*)l, 16, 0, 0);
}

// ---------- P1: x f32 -> bf16 ----------
__global__ __launch_bounds__(256) void k_cast(const float* __restrict__ src,
                                              unsigned short* __restrict__ hi) {
  size_t i = ((size_t)blockIdx.x * 256 + threadIdx.x) * 4;
  float4 v = *(const float4*)(src + i);
  *(ushort4*)(hi + i) = make_ushort4(f2bf(v.x), f2bf(v.y), f2bf(v.z), f2bf(v.w));
}

// ---------- P2/P3: transpose f32 [R][C] -> bf16 [C][R] ----------
__global__ __launch_bounds__(256) void k_transpose(const float* __restrict__ src,
                                                   unsigned short* __restrict__ hi,
                                                   int R, int C) {
  __shared__ float tile[32][33];
  int tx = threadIdx.x & 31, ty = threadIdx.x >> 5;  // ty 0..7
  int c0 = blockIdx.x * 32, r0 = blockIdx.y * 32;
#pragma unroll
  for (int i = 0; i < 4; ++i)
    tile[ty + 8 * i][tx] = src[(size_t)(r0 + ty + 8 * i) * C + (c0 + tx)];
  __syncthreads();
#pragma unroll
  for (int i = 0; i < 4; ++i) {
    float v = tile[tx][ty + 8 * i];
    hi[(size_t)(c0 + ty + 8 * i) * R + (r0 + tx)] = f2bf(v);
  }
}

// ---------- GEMM: A[M][K] (bf16, k-contig), B[N][K] (bf16, k-contig) -> C[M][N]
// 256x256 tile, BK=32, 8 waves (2M x 4N, wave-tile 128x64), 4-buffer LDS ring
// (128KB), prefetch distance 3 K-tiles — R9's proven ring — restructured into
// the m201 two-barriers-per-phase skeleton (the one element never tried):
//   ph1: {ds_read B0-3,A0-3 | stage 2 regions of tile u+3 | BAR | lgkmcnt(0) |
//         sched_barrier | prio1 16 MFMA prio0 | BAR}
//   ph2: {ds_read A4-7 | stage 2 regions | counted vmcnt (certify tile u+1) |
//         BAR | lgkmcnt(0) | sched_barrier | prio1 16 MFMA prio0 | BAR}
// ds_reads+stages issue BEFORE the barrier (latency absorbed by barrier skew);
// MFMA clusters run in dedicated barrier-bracketed windows (m218b's gate).
// vmcnt bookkeeping (per wave, strict tile issue order, 4 gloads/tile):
//   at ph2(u) tail, staged beyond u+1: tiles u+2 (4) + u+3 (4 if staged) ->
//   vmcnt(8) steady / vmcnt(4) when u+3>=nT / vmcnt(0) when u+2>=nT.
//   Tile u+1's last loads were issued at ph2(u-2) — 4 phases (~2000cyc) slack.
// Race-freedom: all waves' tile-(u-1) reads complete before their ph2(u-1)
// lgkmcnt(0) -> before MFMA -> before its trailing barrier; ph1(u)'s stages
// into buf (u-1)&3 issue only after that barrier. Read-after-write: ph2 tail
// vmcnt (own loads) + barrier (collective) certify tile u+1 before ph1(u+1).
// LDS swizzle (verified, conflicts=0): row of 32 k = 4 slots of 8 shorts; phys
// slot p at row r holds global k-chunk p ^ ((r>>1)&3); linear LDS dest +
// pre-swizzled global k on stage; fragment reads apply the same XOR; A and B
// share the lane->k-chunk convention (contraction safe).
template<bool BF16OUT>
__global__ __launch_bounds__(512, 2) void k_gemm(const unsigned short* __restrict__ A,
                                                 const unsigned short* __restrict__ B,
                                                 void* __restrict__ Cv, int M, int N, int K) {
  __shared__ unsigned short lds[65536];      // 4 bufs x 16384 shorts = 128 KB
  const int tid = threadIdx.x, wave = tid >> 6, lane = tid & 63;
  const size_t row0 = (size_t)blockIdx.x * 256;
  const size_t col0 = (size_t)blockIdx.y * 256;
  const int wr = wave >> 2, wc = wave & 3;   // 2M x 4N waves
  const int r16 = lane & 15;
  const int ksw = (lane >> 4) ^ ((r16 >> 1) & 3);       // swizzled k-slot (0..3)
  const int aoff = (wr * 128 + r16) * 32 + ksw * 8;     // A region: shorts 0..8191
  const int boff = 8192 + (wc * 64 + r16) * 32 + ksw * 8;
  const int gchunk = (tid & 3) ^ ((tid >> 3) & 3);      // pre-swizzled global k-chunk

  f32x4 acc[8][4];
#pragma unroll
  for (int i = 0; i < 8; ++i)
#pragma unroll
    for (int j = 0; j < 4; ++j) acc[i][j] = (f32x4){0.f, 0.f, 0.f, 0.f};

  // stage one 8KB region (arr 0=A,1=B; inst 0=rows 0-127,1=rows 128-255) of
  // K-tile kt into ring buffer b. Thread: row inst*128+(tid>>2), 16B at slot tid&3.
  auto SREG = [&](int b, int arr, int inst, int kt) {
    const unsigned short* src = arr ? B : A;
    size_t grow = (arr ? col0 : row0) + (size_t)(inst * 128 + (tid >> 2));
    gload16(src + grow * (size_t)K + (size_t)(kt * 32 + gchunk * 8),
            &lds[(b << 14) + arr * 8192 + inst * 4096 + wave * 512]);
  };

  // prologue: stage tiles 0,1,2 into bufs 0,1,2; certify tile 0
#pragma unroll
  for (int t = 0; t < 3; ++t) {
    SREG(t, 0, 0, t); SREG(t, 0, 1, t);
    SREG(t, 1, 0, t); SREG(t, 1, 1, t);
  }
  asm volatile("s_waitcnt vmcnt(8)" ::: "memory");
  asm volatile("s_barrier" ::: "memory");

  const int nT = K >> 5;
  for (int u = 0; u < nT; ++u) {
    const unsigned short* buf = &lds[(u & 3) << 14];
    const int sb = (u + 3) & 3;
    const bool pf = (u + 3 < nT);

    // ---------- phase 1 ----------
    short8 b4[4], a4[4];
#pragma unroll
    for (int nb = 0; nb < 4; ++nb)
      b4[nb] = *(const short8*)&buf[boff + nb * 512];
#pragma unroll
    for (int mb = 0; mb < 4; ++mb)
      a4[mb] = *(const short8*)&buf[aoff + mb * 512];
    if (pf) { SREG(sb, 0, 0, u + 3); SREG(sb, 0, 1, u + 3); }
    asm volatile("s_barrier" ::: "memory");
    asm volatile("s_waitcnt lgkmcnt(0)" ::: "memory");
    __builtin_amdgcn_sched_barrier(0);
    __builtin_amdgcn_s_setprio(1);
#pragma unroll
    for (int mb = 0; mb < 4; ++mb)
#pragma unroll
      for (int nb = 0; nb < 4; ++nb)
        acc[mb][nb] = __builtin_amdgcn_mfma_f32_16x16x32_bf16(a4[mb], b4[nb], acc[mb][nb], 0, 0, 0);
    __builtin_amdgcn_s_setprio(0);
    asm volatile("s_barrier" ::: "memory");

    // ---------- phase 2 ----------
    short8 a5[4];
#pragma unroll
    for (int mb = 0; mb < 4; ++mb)
      a5[mb] = *(const short8*)&buf[aoff + (4 + mb) * 512];
    if (pf) { SREG(sb, 1, 0, u + 3); SREG(sb, 1, 1, u + 3); }
    // certify tile u+1 for the next iteration (counted, never drain mid-loop)
    if (u + 3 < nT)      asm volatile("s_waitcnt vmcnt(8)" ::: "memory");
    else if (u + 2 < nT) asm volatile("s_waitcnt vmcnt(4)" ::: "memory");
    else if (u + 1 < nT) asm volatile("s_waitcnt vmcnt(0)" ::: "memory");
    asm volatile("s_barrier" ::: "memory");
    asm volatile("s_waitcnt lgkmcnt(0)" ::: "memory");
    __builtin_amdgcn_sched_barrier(0);
    __builtin_amdgcn_s_setprio(1);
#pragma unroll
    for (int mb = 0; mb < 4; ++mb)
#pragma unroll
      for (int nb = 0; nb < 4; ++nb)
        acc[4 + mb][nb] = __builtin_amdgcn_mfma_f32_16x16x32_bf16(a5[mb], b4[nb], acc[4 + mb][nb], 0, 0, 0);
    __builtin_amdgcn_s_setprio(0);
    asm volatile("s_barrier" ::: "memory");
  }

  // C/D layout (HW-verified): col = lane&15, row = (lane>>4)*4 + reg
#pragma unroll
  for (int m = 0; m < 8; ++m)
#pragma unroll
    for (int n = 0; n < 4; ++n) {
      size_t row = row0 + wr * 128 + m * 16 + (lane >> 4) * 4;
      size_t col = col0 + wc * 64 + n * 16 + r16;
      if (BF16OUT) {
        unsigned short* C = (unsigned short*)Cv;
#pragma unroll
        for (int r = 0; r < 4; ++r) C[(row + r) * (size_t)N + col] = f2bf(acc[m][n][r]);
      } else {
        float* C = (float*)Cv;
#pragma unroll
        for (int r = 0; r < 4; ++r) C[(row + r) * (size_t)N + col] = acc[m][n][r];
      }
    }
}

// ---------- scan constants ----------
#define SB 4
#define ST 4096
#define SE 2048
#define CHUNK 64
#define NCHUNK 64
#define NCHAIN (SB * SE)  // 8192

// transforms via native v_exp_f32/v_log_f32 (__expf/__logf), ~1e-7 abs error in
// log-space (irrelevant vs 0.134 budget). proj is bf16.
__device__ __forceinline__ void transform(float k, float hx, float& lc, float& lv) {
  float u = __expf(-fabsf(k));
  float sp = fmaxf(k, 0.f) + __logf(1.f + u);   // softplus(k)
  lc = -sp;                                     // log(1 - sigmoid(k))
  float eh = __expf(fminf(hx, 0.f));            // exp(hx) for hx<0 (clamped: no overflow)
  float arg = (hx >= 0.f) ? (hx + 0.5f) : (1.f + eh);
  float vl = __logf(arg);
  float lg = (hx >= 0.f) ? vl : (hx - vl);      // log g(hx)
  lv = lg + k + lc;                             // log g + log sigmoid(k)
}
__device__ __forceinline__ float lse_step(float lc, float lv, float S) {
  float a1 = lc + S;
  float m = fmaxf(a1, lv);
  float d = fminf(a1, lv) - m;                  // <= 0 (or -inf)
  return m + __logf(1.f + __expf(d));
}

// K2: transforms + chunk-local scan (from -inf) -> chunk summaries ONLY.
__global__ __launch_bounds__(256) void k_scan1(const unsigned short* __restrict__ proj,
                                               const float* __restrict__ bfv,
                                               float* __restrict__ Ac,
                                               float* __restrict__ Bc) {
  int idx = blockIdx.x * 256 + threadIdx.x;  // (c, b, e) with e fastest
  int e = idx & (SE - 1), b = (idx >> 11) & 3, c = idx >> 13;
  const float bk = bfv[e], bh = bfv[SE + e];
  float A = 0.f, S = -INFINITY;
  size_t base = ((size_t)(b * ST + c * CHUNK) * (2 * SE)) + e;
  for (int i = 0; i < CHUNK; ++i) {
    float lc, lv;
    transform(bf2f(proj[base]) + bk, bf2f(proj[base + SE]) + bh, lc, lv);
    A += lc;
    S = lse_step(lc, lv, S);
    base += 2 * SE;
  }
  int chain = b * SE + e;
  Ac[(size_t)c * NCHAIN + chain] = A;
  Bc[(size_t)c * NCHAIN + chain] = S;
}

// K3: scan over chunk summaries -> incoming state per chunk
__global__ __launch_bounds__(256) void k_scan2(const float* __restrict__ lh0,
                                               const float* __restrict__ Ac,
                                               const float* __restrict__ Bc,
                                               float* __restrict__ Hin) {
  int chain = blockIdx.x * 256 + threadIdx.x;  // 8192 = b*E + e
  float H = lh0[chain];
  for (int c = 0; c < NCHUNK; ++c) {
    Hin[(size_t)c * NCHAIN + chain] = H;
    float a = Ac[(size_t)c * NCHAIN + chain] + H;
    float bv = Bc[(size_t)c * NCHAIN + chain];
    float m = fmaxf(a, bv);
    float d = fminf(a, bv) - m;
    H = m + __logf(1.f + __expf(d));
  }
}

// K4: replay scan (recomputing lv/lc from bf16 proj) with true incoming state;
// emit h_t (bf16) and out2 slices (f32)
__global__ __launch_bounds__(256) void k_scan3(const unsigned short* __restrict__ proj,
                                               const float* __restrict__ bfv,
                                               const float* __restrict__ Hin,
                                               unsigned short* __restrict__ ht,
                                               float* __restrict__ out2) {
  int idx = blockIdx.x * 256 + threadIdx.x;
  int e = idx & (SE - 1), b = (idx >> 11) & 3, c = idx >> 13;
  const float bk = bfv[e], bh = bfv[SE + e];
  float S = Hin[(size_t)c * NCHAIN + b * SE + e];
  size_t base = ((size_t)(b * ST + c * CHUNK) * (2 * SE)) + e;
  int t = c * CHUNK;
  size_t hto = ((size_t)(b * ST + t) * SE) + e;
  for (int i = 0; i < CHUNK; ++i, ++t) {
    float lc, lv;
    transform(bf2f(proj[base]) + bk, bf2f(proj[base + SE]) + bh, lc, lv);
    S = lse_step(lc, lv, S);
    ht[hto] = f2bf(__expf(S));
    if (t >= 2 && ((t - 2) % 3) == 0) {   // t in {2,5,...,4094}
      int j = (t - 2) / 3;
      out2[((size_t)b * 1365 + j) * SE + e] = S;
    }
    base += 2 * SE;
    hto += SE;
  }
}

// ---------- launch ----------
extern "C" void kernel_launch(void* const* d_in, const int* in_sizes, int n_in,
                              void* d_out, int out_size, void* d_ws, size_t ws_size,
                              hipStream_t stream) {
  const float* x   = (const float*)d_in[0];
  const float* lh0 = (const float*)d_in[1];
  const float* wf  = (const float*)d_in[2];
  const float* bfv = (const float*)d_in[3];
  const float* wd  = (const float*)d_in[4];
  float* out1 = (float*)d_out;
  float* out2 = out1 + (size_t)SB * ST * 1024;

  char* p = (char*)d_ws;
  unsigned short* proj = (unsigned short*)p; p += 16384ull * 4096 * 2;  // 134 MB bf16
  unsigned short* xhi  = (unsigned short*)p; p += 16384ull * 1024 * 2;
  unsigned short* wfh  = (unsigned short*)p; p += 4096ull * 1024 * 2;
  unsigned short* wdt  = (unsigned short*)p; p += 1024ull * 2048 * 2;
  unsigned short* ht   = (unsigned short*)p; p += 16384ull * 2048 * 2;  // 67 MB
  float* Ac            = (float*)p;          p += 64ull * 8192 * 4;
  float* Bc            = (float*)p;          p += 64ull * 8192 * 4;
  float* Hin           = (float*)p;          p += 64ull * 8192 * 4;

  // pre-passes
  hipLaunchKernelGGL(k_cast, dim3(16384), dim3(256), 0, stream, x, xhi);
  hipLaunchKernelGGL(k_transpose, dim3(128, 32), dim3(256), 0, stream, wf, wfh, 1024, 4096);
  hipLaunchKernelGGL(k_transpose, dim3(32, 64),  dim3(256), 0, stream, wd, wdt, 2048, 1024);
  // GEMM1 (bf16 in/out): proj = x @ w_f
  hipLaunchKernelGGL((k_gemm<true>), dim3(64, 16), dim3(512), 0, stream,
                     xhi, wfh, (void*)proj, 16384, 4096, 1024);
  // 3-pass chunked log-space scan (proj bf16, read-only; scan3 recomputes)
  hipLaunchKernelGGL(k_scan1, dim3(2048), dim3(256), 0, stream, proj, bfv, Ac, Bc);
  hipLaunchKernelGGL(k_scan2, dim3(32), dim3(256), 0, stream, lh0, Ac, Bc, Hin);
  hipLaunchKernelGGL(k_scan3, dim3(2048), dim3(256), 0, stream, proj, bfv, Hin, ht, out2);
  // GEMM2 (bf16 in, f32 out): out1 = h_t @ w_down
  hipLaunchKernelGGL((k_gemm<false>), dim3(64, 4), dim3(512), 0, stream,
                     ht, wdt, (void*)out1, 16384, 1024, 2048);
}

// Round 12
// 319.402 us; speedup vs baseline: 1.3000x; 1.2186x over previous
//
#include <hip/hip_runtime.h>
#include <cstdint>
#include <cstddef>

typedef __attribute__((ext_vector_type(4))) float f32x4;
typedef __attribute__((ext_vector_type(8))) short short8;

// ---------- bf16 helpers (bit-level, header-version independent) ----------
__device__ __forceinline__ unsigned short f2bf(float f) {
  unsigned int u = __float_as_uint(f);
  u += 0x7fffu + ((u >> 16) & 1u);            // round to nearest even
  return (unsigned short)(u >> 16);
}
__device__ __forceinline__ float bf2f(unsigned short h) {
  return __uint_as_float(((unsigned int)h) << 16);
}

__device__ __forceinline__ void gload16(const unsigned short* g, unsigned short* l) {
  __builtin_amdgcn_global_load_lds(
      (const __attribute__((address_space(1))) void*)g,
      (__attribute__((address_space(3))) void*)l, 16, 0, 0);
}

// ---------- P1: x f32 -> bf16 ----------
__global__ __launch_bounds__(256) void k_cast(const float* __restrict__ src,
                                              unsigned short* __restrict__ hi) {
  size_t i = ((size_t)blockIdx.x * 256 + threadIdx.x) * 4;
  float4 v = *(const float4*)(src + i);
  *(ushort4*)(hi + i) = make_ushort4(f2bf(v.x), f2bf(v.y), f2bf(v.z), f2bf(v.w));
}

// ---------- P2/P3: transpose f32 [R][C] -> bf16 [C][R] ----------
__global__ __launch_bounds__(256) void k_transpose(const float* __restrict__ src,
                                                   unsigned short* __restrict__ hi,
                                                   int R, int C) {
  __shared__ float tile[32][33];
  int tx = threadIdx.x & 31, ty = threadIdx.x >> 5;  // ty 0..7
  int c0 = blockIdx.x * 32, r0 = blockIdx.y * 32;
#pragma unroll
  for (int i = 0; i < 4; ++i)
    tile[ty + 8 * i][tx] = src[(size_t)(r0 + ty + 8 * i) * C + (c0 + tx)];
  __syncthreads();
#pragma unroll
  for (int i = 0; i < 4; ++i) {
    float v = tile[tx][ty + 8 * i];
    hi[(size_t)(c0 + ty + 8 * i) * R + (r0 + tx)] = f2bf(v);
  }
}

// ---------- GEMM (R8 exact — best measured: 138us, MfmaUtil 44; R9-R11 schedule
// variants all 38-45% -> plateau declared, do not touch) ----------
// 256x256 tile, BK=32, 8 waves (2M x 4N, wave-tile 128x64), 4-buffer LDS ring
// (128KB), prefetch distance 3 K-tiles. Per K-tile: ONE counted vmcnt + ONE raw
// s_barrier, then two half-phases {ds_read, stage 2 regions, 16 MFMA (prio1)}.
// vmcnt: per-wave strict tile issue order, 4 gloads/tile; at tile u's wait
// in-flight <= tiles u,u+1,u+2 = 12 loads; vmcnt(8) -> tile u landed (m135
// oldest-first). Tail: rem==1 -> vmcnt(4), rem==0 -> vmcnt(0). Wait BEFORE
// barrier => collective completeness. Writes of tile u+3 (buf (u-1)&3) issue
// after ph(u)'s barrier => all waves already consumed tile u-1.
// LDS swizzle (verified, conflicts=0): row of 32 k = 4 slots of 8 shorts; phys
// slot p at row r holds global k-chunk p ^ ((r>>1)&3); linear LDS dest +
// pre-swizzled global k on stage; fragment reads apply the same XOR; A and B
// share the lane->k-chunk convention (contraction safe).
template<bool BF16OUT>
__global__ __launch_bounds__(512, 2) void k_gemm(const unsigned short* __restrict__ A,
                                                 const unsigned short* __restrict__ B,
                                                 void* __restrict__ Cv, int M, int N, int K) {
  __shared__ unsigned short lds[65536];      // 4 bufs x 16384 shorts = 128 KB
  const int tid = threadIdx.x, wave = tid >> 6, lane = tid & 63;
  const size_t row0 = (size_t)blockIdx.x * 256;
  const size_t col0 = (size_t)blockIdx.y * 256;
  const int wr = wave >> 2, wc = wave & 3;   // 2M x 4N waves
  const int r16 = lane & 15;
  const int ksw = (lane >> 4) ^ ((r16 >> 1) & 3);       // swizzled k-slot (0..3)
  const int aoff = (wr * 128 + r16) * 32 + ksw * 8;     // A region: shorts 0..8191
  const int boff = 8192 + (wc * 64 + r16) * 32 + ksw * 8;
  const int gchunk = (tid & 3) ^ ((tid >> 3) & 3);      // pre-swizzled global k-chunk

  f32x4 acc[8][4];
#pragma unroll
  for (int i = 0; i < 8; ++i)
#pragma unroll
    for (int j = 0; j < 4; ++j) acc[i][j] = (f32x4){0.f, 0.f, 0.f, 0.f};

  auto SREG = [&](int b, int arr, int inst, int kt) {
    const unsigned short* src = arr ? B : A;
    size_t grow = (arr ? col0 : row0) + (size_t)(inst * 128 + (tid >> 2));
    gload16(src + grow * (size_t)K + (size_t)(kt * 32 + gchunk * 8),
            &lds[(b << 14) + arr * 8192 + inst * 4096 + wave * 512]);
  };

  // prologue: stage tiles 0,1,2 into bufs 0,1,2
#pragma unroll
  for (int t = 0; t < 3; ++t) {
    SREG(t, 0, 0, t); SREG(t, 0, 1, t);
    SREG(t, 1, 0, t); SREG(t, 1, 1, t);
  }

  const int nT = K >> 5;
  for (int u = 0; u < nT; ++u) {
    const unsigned short* buf = &lds[(u & 3) << 14];
    const int sb = (u + 3) & 3;
    const bool pf = (u + 3 < nT);
    const int rem = nT - 1 - u;
    if (rem >= 2)      asm volatile("s_waitcnt vmcnt(8)" ::: "memory");
    else if (rem == 1) asm volatile("s_waitcnt vmcnt(4)" ::: "memory");
    else               asm volatile("s_waitcnt vmcnt(0)" ::: "memory");
    asm volatile("s_barrier" ::: "memory");
    short8 a4[4], b4[4];
#pragma unroll
    for (int nb = 0; nb < 4; ++nb)
      b4[nb] = *(const short8*)&buf[boff + nb * 512];
#pragma unroll
    for (int mb = 0; mb < 4; ++mb)
      a4[mb] = *(const short8*)&buf[aoff + mb * 512];
    if (pf) { SREG(sb, 0, 0, u + 3); SREG(sb, 1, 0, u + 3); }
    __builtin_amdgcn_s_setprio(1);
#pragma unroll
    for (int mb = 0; mb < 4; ++mb)
#pragma unroll
      for (int nb = 0; nb < 4; ++nb)
        acc[mb][nb] = __builtin_amdgcn_mfma_f32_16x16x32_bf16(a4[mb], b4[nb], acc[mb][nb], 0, 0, 0);
    __builtin_amdgcn_s_setprio(0);
#pragma unroll
    for (int mb = 0; mb < 4; ++mb)
      a4[mb] = *(const short8*)&buf[aoff + (4 + mb) * 512];
    if (pf) { SREG(sb, 0, 1, u + 3); SREG(sb, 1, 1, u + 3); }
    __builtin_amdgcn_s_setprio(1);
#pragma unroll
    for (int mb = 0; mb < 4; ++mb)
#pragma unroll
      for (int nb = 0; nb < 4; ++nb)
        acc[4 + mb][nb] = __builtin_amdgcn_mfma_f32_16x16x32_bf16(a4[mb], b4[nb], acc[4 + mb][nb], 0, 0, 0);
    __builtin_amdgcn_s_setprio(0);
  }

  // C/D layout (HW-verified): col = lane&15, row = (lane>>4)*4 + reg
#pragma unroll
  for (int m = 0; m < 8; ++m)
#pragma unroll
    for (int n = 0; n < 4; ++n) {
      size_t row = row0 + wr * 128 + m * 16 + (lane >> 4) * 4;
      size_t col = col0 + wc * 64 + n * 16 + r16;
      if (BF16OUT) {
        unsigned short* C = (unsigned short*)Cv;
#pragma unroll
        for (int r = 0; r < 4; ++r) C[(row + r) * (size_t)N + col] = f2bf(acc[m][n][r]);
      } else {
        float* C = (float*)Cv;
#pragma unroll
        for (int r = 0; r < 4; ++r) C[(row + r) * (size_t)N + col] = acc[m][n][r];
      }
    }
}

// ---------- scan constants ----------
#define SB 4
#define ST 4096
#define SE 2048
#define CHUNK 64
#define NCHUNK 64
#define NCHAIN (SB * SE)  // 8192

// LINEAR-SPACE scan (replaces log-space): h_t = c*h_{t-1} + v with
// c = sigmoid(-k), v = sigmoid(k)*g(hx), all positive, h in [~1e-7, ~150]
// -> f32-safe, no under/overflow that matters (chunk product A may flush to 0
// = correct: history term then <=1e-20 of B). Cancellation-free c via
// c = e^-k * rcp(1+e^-k) (NOT 1-sigmoid). Per-step rel err ~1e-7, accumulates
// to ~1e-3 in log h over T=4096 — far inside the 0.134 budget.
// Inner loop: 2 v_exp + 2 v_rcp + ~8 VALU; serial S-chain = ONE fma
// (was exp->log chain of the log-space lse_step).
__device__ __forceinline__ void transform_lin(float k, float hx, float& c, float& v) {
  float e = __expf(-k);
  float r = __builtin_amdgcn_rcpf(1.f + e);    // sigmoid(k), 1ulp
  c = e * r;                                   // sigmoid(-k), no cancellation
  float e2 = __expf(-hx);
  float sg = __builtin_amdgcn_rcpf(1.f + e2);  // sigmoid(hx)
  float g = (hx >= 0.f) ? (hx + 0.5f) : sg;    // g(hx)
  v = r * g;
}

// K2: transforms + chunk-local linear scan (from 0) -> chunk summaries
// A = prod c, B = local h. proj read-only.
__global__ __launch_bounds__(256) void k_scan1(const unsigned short* __restrict__ proj,
                                               const float* __restrict__ bfv,
                                               float* __restrict__ Ac,
                                               float* __restrict__ Bc) {
  int idx = blockIdx.x * 256 + threadIdx.x;  // (c, b, e) with e fastest
  int e = idx & (SE - 1), b = (idx >> 11) & 3, c = idx >> 13;
  const float bk = bfv[e], bh = bfv[SE + e];
  float A = 1.f, S = 0.f;
  size_t base = ((size_t)(b * ST + c * CHUNK) * (2 * SE)) + e;
  for (int i = 0; i < CHUNK; ++i) {
    float cc, vv;
    transform_lin(bf2f(proj[base]) + bk, bf2f(proj[base + SE]) + bh, cc, vv);
    A *= cc;
    S = fmaf(cc, S, vv);
    base += 2 * SE;
  }
  int chain = b * SE + e;
  Ac[(size_t)c * NCHAIN + chain] = A;
  Bc[(size_t)c * NCHAIN + chain] = S;
}

// K3: scan over chunk summaries (linear): H_{c+1} = A_c*H_c + B_c; H_0 = exp(lh0)
__global__ __launch_bounds__(256) void k_scan2(const float* __restrict__ lh0,
                                               const float* __restrict__ Ac,
                                               const float* __restrict__ Bc,
                                               float* __restrict__ Hin) {
  int chain = blockIdx.x * 256 + threadIdx.x;  // 8192 = b*E + e
  float H = __expf(lh0[chain]);
  for (int c = 0; c < NCHUNK; ++c) {
    Hin[(size_t)c * NCHAIN + chain] = H;
    H = fmaf(Ac[(size_t)c * NCHAIN + chain], H, Bc[(size_t)c * NCHAIN + chain]);
  }
}

// K4: replay linear scan with true incoming state; emit h_t (bf16, no exp
// needed!) and out2 = log(h) slices (f32, __logf only on 1/3 of steps)
__global__ __launch_bounds__(256) void k_scan3(const unsigned short* __restrict__ proj,
                                               const float* __restrict__ bfv,
                                               const float* __restrict__ Hin,
                                               unsigned short* __restrict__ ht,
                                               float* __restrict__ out2) {
  int idx = blockIdx.x * 256 + threadIdx.x;
  int e = idx & (SE - 1), b = (idx >> 11) & 3, c = idx >> 13;
  const float bk = bfv[e], bh = bfv[SE + e];
  float S = Hin[(size_t)c * NCHAIN + b * SE + e];
  size_t base = ((size_t)(b * ST + c * CHUNK) * (2 * SE)) + e;
  int t = c * CHUNK;
  size_t hto = ((size_t)(b * ST + t) * SE) + e;
  for (int i = 0; i < CHUNK; ++i, ++t) {
    float cc, vv;
    transform_lin(bf2f(proj[base]) + bk, bf2f(proj[base + SE]) + bh, cc, vv);
    S = fmaf(cc, S, vv);
    ht[hto] = f2bf(S);
    if (t >= 2 && ((t - 2) % 3) == 0) {   // t in {2,5,...,4094}
      int j = (t - 2) / 3;
      out2[((size_t)b * 1365 + j) * SE + e] = __logf(S);
    }
    base += 2 * SE;
    hto += SE;
  }
}

// ---------- launch ----------
extern "C" void kernel_launch(void* const* d_in, const int* in_sizes, int n_in,
                              void* d_out, int out_size, void* d_ws, size_t ws_size,
                              hipStream_t stream) {
  const float* x   = (const float*)d_in[0];
  const float* lh0 = (const float*)d_in[1];
  const float* wf  = (const float*)d_in[2];
  const float* bfv = (const float*)d_in[3];
  const float* wd  = (const float*)d_in[4];
  float* out1 = (float*)d_out;
  float* out2 = out1 + (size_t)SB * ST * 1024;

  char* p = (char*)d_ws;
  unsigned short* proj = (unsigned short*)p; p += 16384ull * 4096 * 2;  // 134 MB bf16
  unsigned short* xhi  = (unsigned short*)p; p += 16384ull * 1024 * 2;
  unsigned short* wfh  = (unsigned short*)p; p += 4096ull * 1024 * 2;
  unsigned short* wdt  = (unsigned short*)p; p += 1024ull * 2048 * 2;
  unsigned short* ht   = (unsigned short*)p; p += 16384ull * 2048 * 2;  // 67 MB
  float* Ac            = (float*)p;          p += 64ull * 8192 * 4;
  float* Bc            = (float*)p;          p += 64ull * 8192 * 4;
  float* Hin           = (float*)p;          p += 64ull * 8192 * 4;

  // pre-passes
  hipLaunchKernelGGL(k_cast, dim3(16384), dim3(256), 0, stream, x, xhi);
  hipLaunchKernelGGL(k_transpose, dim3(128, 32), dim3(256), 0, stream, wf, wfh, 1024, 4096);
  hipLaunchKernelGGL(k_transpose, dim3(32, 64),  dim3(256), 0, stream, wd, wdt, 2048, 1024);
  // GEMM1 (bf16 in/out): proj = x @ w_f
  hipLaunchKernelGGL((k_gemm<true>), dim3(64, 16), dim3(512), 0, stream,
                     xhi, wfh, (void*)proj, 16384, 4096, 1024);
  // 3-pass chunked LINEAR-space scan (proj bf16, read-only; scan3 recomputes)
  hipLaunchKernelGGL(k_scan1, dim3(2048), dim3(256), 0, stream, proj, bfv, Ac, Bc);
  hipLaunchKernelGGL(k_scan2, dim3(32), dim3(256), 0, stream, lh0, Ac, Bc, Hin);
  hipLaunchKernelGGL(k_scan3, dim3(2048), dim3(256), 0, stream, proj, bfv, Hin, ht, out2);
  // GEMM2 (bf16 in, f32 out): out1 = h_t @ w_down
  hipLaunchKernelGGL((k_gemm<false>), dim3(64, 4), dim3(512), 0, stream,
                     ht, wdt, (void*)out1, 16384, 1024, 2048);
}

// Round 13
// 309.041 us; speedup vs baseline: 1.3435x; 1.0335x over previous
//
#include <hip/hip_runtime.h>
#include <cstdint>
#include <cstddef>

typedef __attribute__((ext_vector_type(4))) float f32x4;
typedef __attribute__((ext_vector_type(8))) short short8;

// ---------- bf16 helpers (bit-level, header-version independent) ----------
__device__ __forceinline__ unsigned short f2bf(float f) {
  unsigned int u = __float_as_uint(f);
  u += 0x7fffu + ((u >> 16) & 1u);            // round to nearest even
  return (unsigned short)(u >> 16);
}
__device__ __forceinline__ float bf2f(unsigned short h) {
  return __uint_as_float(((unsigned int)h) << 16);
}
__device__ __forceinline__ float bflo(unsigned int w) {   // low bf16 of a word
  return __uint_as_float(w << 16);
}
__device__ __forceinline__ float bfhi(unsigned int w) {   // high bf16 of a word
  return __uint_as_float(w & 0xffff0000u);
}

__device__ __forceinline__ void gload16(const unsigned short* g, unsigned short* l) {
  __builtin_amdgcn_global_load_lds(
      (const __attribute__((address_space(1))) void*)g,
      (__attribute__((address_space(3))) void*)l, 16, 0, 0);
}

// ---------- merged pre-pass: cast x, transpose+interleave wf, transpose wd,
// pack biases. One launch, block-range dispatch (independent jobs). ----------
// wfh row layout: phi(j) = j<2048 ? 2j : 2(j-2048)+1  ->  proj col 2e = k_e,
// col 2e+1 = hx_e: scans read ONE coalesced u32 per step (was 2x 2B scalar
// bf16 loads = half-rate; G13).
__global__ __launch_bounds__(256) void k_prep(const float* __restrict__ x,
                                              unsigned short* __restrict__ xhi,
                                              const float* __restrict__ wf,
                                              unsigned short* __restrict__ wfh,
                                              const float* __restrict__ wd,
                                              unsigned short* __restrict__ wdt,
                                              const float* __restrict__ bfv,
                                              float2* __restrict__ bfi) {
  int blk = blockIdx.x;
  if (blk < 16384) {                       // cast x f32 -> bf16 (16384 blocks)
    size_t i = ((size_t)blk * 256 + threadIdx.x) * 4;
    float4 v = *(const float4*)(x + i);
    *(ushort4*)(xhi + i) = make_ushort4(f2bf(v.x), f2bf(v.y), f2bf(v.z), f2bf(v.w));
    return;
  }
  blk -= 16384;
  if (blk < 4096) {                        // wf [1024][4096] -> wfh interleaved [4096][1024]
    __shared__ float tile[32][33];
    int tx = threadIdx.x & 31, ty = threadIdx.x >> 5;
    int bx = blk & 127, by = blk >> 7;     // 128 x 32
    int c0 = bx * 32, r0 = by * 32;
#pragma unroll
    for (int i = 0; i < 4; ++i)
      tile[ty + 8 * i][tx] = wf[(size_t)(r0 + ty + 8 * i) * 4096 + (c0 + tx)];
    __syncthreads();
#pragma unroll
    for (int i = 0; i < 4; ++i) {
      int j = c0 + ty + 8 * i;             // original wf column
      int r = (j < 2048) ? (2 * j) : (2 * (j - 2048) + 1);
      wfh[(size_t)r * 1024 + (r0 + tx)] = f2bf(tile[tx][ty + 8 * i]);
    }
    return;
  }
  blk -= 4096;
  if (blk < 2048) {                        // wd [2048][1024] -> wdt [1024][2048]
    __shared__ float tile[32][33];
    int tx = threadIdx.x & 31, ty = threadIdx.x >> 5;
    int bx = blk & 31, by = blk >> 5;      // 32 x 64
    int c0 = bx * 32, r0 = by * 32;
#pragma unroll
    for (int i = 0; i < 4; ++i)
      tile[ty + 8 * i][tx] = wd[(size_t)(r0 + ty + 8 * i) * 1024 + (c0 + tx)];
    __syncthreads();
#pragma unroll
    for (int i = 0; i < 4; ++i)
      wdt[(size_t)(c0 + ty + 8 * i) * 2048 + (r0 + tx)] = f2bf(tile[tx][ty + 8 * i]);
    return;
  }
  blk -= 2048;                             // bias pack: bfi[e] = (b_f[e], b_f[2048+e])
  int i = blk * 256 + threadIdx.x;
  if (i < 2048) bfi[i] = make_float2(bfv[i], bfv[2048 + i]);
}

// ---------- GEMM (R8/R12 exact — best measured: 138us, MfmaUtil 44; schedule
// plateau declared after R9-R11 variants all landed 38-45%. DO NOT TOUCH) ----
// 256x256 tile, BK=32, 8 waves (2M x 4N, wave-tile 128x64), 4-buffer LDS ring
// (128KB), prefetch distance 3 K-tiles. Per K-tile: ONE counted vmcnt + ONE raw
// s_barrier, then two half-phases {ds_read, stage 2 regions, 16 MFMA (prio1)}.
// vmcnt: per-wave strict tile issue order, 4 gloads/tile; at tile u's wait
// in-flight <= tiles u,u+1,u+2 = 12 loads; vmcnt(8) -> tile u landed (m135
// oldest-first). Tail: rem==1 -> vmcnt(4), rem==0 -> vmcnt(0). Wait BEFORE
// barrier => collective completeness. Writes of tile u+3 (buf (u-1)&3) issue
// after ph(u)'s barrier => all waves already consumed tile u-1.
// LDS swizzle (verified, conflicts=0): row of 32 k = 4 slots of 8 shorts; phys
// slot p at row r holds global k-chunk p ^ ((r>>1)&3); linear LDS dest +
// pre-swizzled global k on stage; fragment reads apply the same XOR; A and B
// share the lane->k-chunk convention (contraction safe).
template<bool BF16OUT>
__global__ __launch_bounds__(512, 2) void k_gemm(const unsigned short* __restrict__ A,
                                                 const unsigned short* __restrict__ B,
                                                 void* __restrict__ Cv, int M, int N, int K) {
  __shared__ unsigned short lds[65536];      // 4 bufs x 16384 shorts = 128 KB
  const int tid = threadIdx.x, wave = tid >> 6, lane = tid & 63;
  const size_t row0 = (size_t)blockIdx.x * 256;
  const size_t col0 = (size_t)blockIdx.y * 256;
  const int wr = wave >> 2, wc = wave & 3;   // 2M x 4N waves
  const int r16 = lane & 15;
  const int ksw = (lane >> 4) ^ ((r16 >> 1) & 3);       // swizzled k-slot (0..3)
  const int aoff = (wr * 128 + r16) * 32 + ksw * 8;     // A region: shorts 0..8191
  const int boff = 8192 + (wc * 64 + r16) * 32 + ksw * 8;
  const int gchunk = (tid & 3) ^ ((tid >> 3) & 3);      // pre-swizzled global k-chunk

  f32x4 acc[8][4];
#pragma unroll
  for (int i = 0; i < 8; ++i)
#pragma unroll
    for (int j = 0; j < 4; ++j) acc[i][j] = (f32x4){0.f, 0.f, 0.f, 0.f};

  auto SREG = [&](int b, int arr, int inst, int kt) {
    const unsigned short* src = arr ? B : A;
    size_t grow = (arr ? col0 : row0) + (size_t)(inst * 128 + (tid >> 2));
    gload16(src + grow * (size_t)K + (size_t)(kt * 32 + gchunk * 8),
            &lds[(b << 14) + arr * 8192 + inst * 4096 + wave * 512]);
  };

  // prologue: stage tiles 0,1,2 into bufs 0,1,2
#pragma unroll
  for (int t = 0; t < 3; ++t) {
    SREG(t, 0, 0, t); SREG(t, 0, 1, t);
    SREG(t, 1, 0, t); SREG(t, 1, 1, t);
  }

  const int nT = K >> 5;
  for (int u = 0; u < nT; ++u) {
    const unsigned short* buf = &lds[(u & 3) << 14];
    const int sb = (u + 3) & 3;
    const bool pf = (u + 3 < nT);
    const int rem = nT - 1 - u;
    if (rem >= 2)      asm volatile("s_waitcnt vmcnt(8)" ::: "memory");
    else if (rem == 1) asm volatile("s_waitcnt vmcnt(4)" ::: "memory");
    else               asm volatile("s_waitcnt vmcnt(0)" ::: "memory");
    asm volatile("s_barrier" ::: "memory");
    short8 a4[4], b4[4];
#pragma unroll
    for (int nb = 0; nb < 4; ++nb)
      b4[nb] = *(const short8*)&buf[boff + nb * 512];
#pragma unroll
    for (int mb = 0; mb < 4; ++mb)
      a4[mb] = *(const short8*)&buf[aoff + mb * 512];
    if (pf) { SREG(sb, 0, 0, u + 3); SREG(sb, 1, 0, u + 3); }
    __builtin_amdgcn_s_setprio(1);
#pragma unroll
    for (int mb = 0; mb < 4; ++mb)
#pragma unroll
      for (int nb = 0; nb < 4; ++nb)
        acc[mb][nb] = __builtin_amdgcn_mfma_f32_16x16x32_bf16(a4[mb], b4[nb], acc[mb][nb], 0, 0, 0);
    __builtin_amdgcn_s_setprio(0);
#pragma unroll
    for (int mb = 0; mb < 4; ++mb)
      a4[mb] = *(const short8*)&buf[aoff + (4 + mb) * 512];
    if (pf) { SREG(sb, 0, 1, u + 3); SREG(sb, 1, 1, u + 3); }
    __builtin_amdgcn_s_setprio(1);
#pragma unroll
    for (int mb = 0; mb < 4; ++mb)
#pragma unroll
      for (int nb = 0; nb < 4; ++nb)
        acc[4 + mb][nb] = __builtin_amdgcn_mfma_f32_16x16x32_bf16(a4[mb], b4[nb], acc[4 + mb][nb], 0, 0, 0);
    __builtin_amdgcn_s_setprio(0);
  }

  // C/D layout (HW-verified): col = lane&15, row = (lane>>4)*4 + reg
#pragma unroll
  for (int m = 0; m < 8; ++m)
#pragma unroll
    for (int n = 0; n < 4; ++n) {
      size_t row = row0 + wr * 128 + m * 16 + (lane >> 4) * 4;
      size_t col = col0 + wc * 64 + n * 16 + r16;
      if (BF16OUT) {
        unsigned short* C = (unsigned short*)Cv;
#pragma unroll
        for (int r = 0; r < 4; ++r) C[(row + r) * (size_t)N + col] = f2bf(acc[m][n][r]);
      } else {
        float* C = (float*)Cv;
#pragma unroll
        for (int r = 0; r < 4; ++r) C[(row + r) * (size_t)N + col] = acc[m][n][r];
      }
    }
}

// ---------- scan constants ----------
#define SB 4
#define ST 4096
#define SE 2048
#define CHUNK 64
#define NCHUNK 64
#define NCHAIN (SB * SE)  // 8192

// LINEAR-SPACE scan: h_t = c*h_{t-1} + v, c = sigmoid(-k), v = sigmoid(k)*g(hx),
// all positive, h in [~1e-7, ~150] — f32-safe (chunk product A may flush to 0 =
// correct). Cancellation-free c = e^-k * rcp(1+e^-k). Per-step rel err ~1e-7.
// proj layout INTERLEAVED: word e of a row = (k_e lo, hx_e hi) — one coalesced
// u32 load per thread-step.
__device__ __forceinline__ void transform_lin(float k, float hx, float& c, float& v) {
  float e = __expf(-k);
  float r = __builtin_amdgcn_rcpf(1.f + e);    // sigmoid(k)
  c = e * r;                                   // sigmoid(-k), no cancellation
  float e2 = __expf(-hx);
  float sg = __builtin_amdgcn_rcpf(1.f + e2);  // sigmoid(hx)
  float g = (hx >= 0.f) ? (hx + 0.5f) : sg;    // g(hx)
  v = r * g;
}

// K2: transforms + chunk-local linear scan (from 0) -> chunk summaries
__global__ __launch_bounds__(256) void k_scan1(const unsigned int* __restrict__ proj32,
                                               const float2* __restrict__ bfi,
                                               float* __restrict__ Ac,
                                               float* __restrict__ Bc) {
  int idx = blockIdx.x * 256 + threadIdx.x;  // (c, b, e) with e fastest
  int e = idx & (SE - 1), b = (idx >> 11) & 3, c = idx >> 13;
  const float2 bb = bfi[e];
  float A = 1.f, S = 0.f;
  size_t base = ((size_t)(b * ST + c * CHUNK)) * SE + e;   // word index, row = 2048 words
  for (int i = 0; i < CHUNK; ++i) {
    unsigned int w = proj32[base];
    float cc, vv;
    transform_lin(bflo(w) + bb.x, bfhi(w) + bb.y, cc, vv);
    A *= cc;
    S = fmaf(cc, S, vv);
    base += SE;
  }
  int chain = b * SE + e;
  Ac[(size_t)c * NCHAIN + chain] = A;
  Bc[(size_t)c * NCHAIN + chain] = S;
}

// K3: scan over chunk summaries (linear): H_{c+1} = A_c*H_c + B_c; H_0 = exp(lh0)
__global__ __launch_bounds__(256) void k_scan2(const float* __restrict__ lh0,
                                               const float* __restrict__ Ac,
                                               const float* __restrict__ Bc,
                                               float* __restrict__ Hin) {
  int chain = blockIdx.x * 256 + threadIdx.x;  // 8192 = b*E + e
  float H = __expf(lh0[chain]);
  for (int c = 0; c < NCHUNK; ++c) {
    Hin[(size_t)c * NCHAIN + chain] = H;
    H = fmaf(Ac[(size_t)c * NCHAIN + chain], H, Bc[(size_t)c * NCHAIN + chain]);
  }
}

// K4: replay linear scan with true incoming state; emit h_t (bf16) and
// out2 = log(h) slices (f32, __logf only on 1/3 of steps)
__global__ __launch_bounds__(256) void k_scan3(const unsigned int* __restrict__ proj32,
                                               const float2* __restrict__ bfi,
                                               const float* __restrict__ Hin,
                                               unsigned short* __restrict__ ht,
                                               float* __restrict__ out2) {
  int idx = blockIdx.x * 256 + threadIdx.x;
  int e = idx & (SE - 1), b = (idx >> 11) & 3, c = idx >> 13;
  const float2 bb = bfi[e];
  float S = Hin[(size_t)c * NCHAIN + b * SE + e];
  size_t base = ((size_t)(b * ST + c * CHUNK)) * SE + e;
  int t = c * CHUNK;
  size_t hto = ((size_t)(b * ST + t)) * SE + e;
  for (int i = 0; i < CHUNK; ++i, ++t) {
    unsigned int w = proj32[base];
    float cc, vv;
    transform_lin(bflo(w) + bb.x, bfhi(w) + bb.y, cc, vv);
    S = fmaf(cc, S, vv);
    ht[hto] = f2bf(S);
    if (t >= 2 && ((t - 2) % 3) == 0) {   // t in {2,5,...,4094}
      int j = (t - 2) / 3;
      out2[((size_t)b * 1365 + j) * SE + e] = __logf(S);
    }
    base += SE;
    hto += SE;
  }
}

// ---------- launch ----------
extern "C" void kernel_launch(void* const* d_in, const int* in_sizes, int n_in,
                              void* d_out, int out_size, void* d_ws, size_t ws_size,
                              hipStream_t stream) {
  const float* x   = (const float*)d_in[0];
  const float* lh0 = (const float*)d_in[1];
  const float* wf  = (const float*)d_in[2];
  const float* bfv = (const float*)d_in[3];
  const float* wd  = (const float*)d_in[4];
  float* out1 = (float*)d_out;
  float* out2 = out1 + (size_t)SB * ST * 1024;

  char* p = (char*)d_ws;
  unsigned short* proj = (unsigned short*)p; p += 16384ull * 4096 * 2;  // 134 MB bf16
  unsigned short* xhi  = (unsigned short*)p; p += 16384ull * 1024 * 2;
  unsigned short* wfh  = (unsigned short*)p; p += 4096ull * 1024 * 2;
  unsigned short* wdt  = (unsigned short*)p; p += 1024ull * 2048 * 2;
  unsigned short* ht   = (unsigned short*)p; p += 16384ull * 2048 * 2;  // 67 MB
  float* Ac            = (float*)p;          p += 64ull * 8192 * 4;
  float* Bc            = (float*)p;          p += 64ull * 8192 * 4;
  float* Hin           = (float*)p;          p += 64ull * 8192 * 4;
  float2* bfi          = (float2*)p;         p += 2048ull * 8;

  // merged pre-pass (cast + transpose-interleave wf + transpose wd + bias pack)
  hipLaunchKernelGGL(k_prep, dim3(16384 + 4096 + 2048 + 8), dim3(256), 0, stream,
                     x, xhi, wf, wfh, wd, wdt, bfv, bfi);
  // GEMM1 (bf16 in/out): proj = x @ w_f (cols interleaved via wfh row perm)
  hipLaunchKernelGGL((k_gemm<true>), dim3(64, 16), dim3(512), 0, stream,
                     xhi, wfh, (void*)proj, 16384, 4096, 1024);
  // 3-pass chunked LINEAR-space scan (proj read-only, word-coalesced)
  hipLaunchKernelGGL(k_scan1, dim3(2048), dim3(256), 0, stream,
                     (const unsigned int*)proj, bfi, Ac, Bc);
  hipLaunchKernelGGL(k_scan2, dim3(32), dim3(256), 0, stream, lh0, Ac, Bc, Hin);
  hipLaunchKernelGGL(k_scan3, dim3(2048), dim3(256), 0, stream,
                     (const unsigned int*)proj, bfi, Hin, ht, out2);
  // GEMM2 (bf16 in, f32 out): out1 = h_t @ w_down
  hipLaunchKernelGGL((k_gemm<false>), dim3(64, 4), dim3(512), 0, stream,
                     ht, wdt, (void*)out1, 16384, 1024, 2048);
}